// Round 4
// baseline (731.970 us; speedup 1.0000x reference)
//
#include <hip/hip_runtime.h>
#include <hip/hip_bf16.h>
#include <stdint.h>

#define N 8192
#define D 128
#define NCHUNK 16
#define CHUNK (N / NCHUNK)      // 512 cols per chunk
#define RT 128                  // rows per block (4 waves x 32)
#define CT 64                   // cols per LDS tile
#define NTILES (CHUNK / CT)     // 8

typedef short bf16x8 __attribute__((ext_vector_type(8)));
typedef float f32x4 __attribute__((ext_vector_type(4)));
typedef unsigned int uint32;
typedef unsigned long long uint64;

// ---- workspace layout (bytes) ----
#define OFF_ACC   0u                          // [0] float S_sum, [4] uint32 P_count
#define OFF_SQ2   1024u                       // 8192 floats
#define OFF_M     40960u                      // NCHUNK*N floats
#define OFF_L     (OFF_M + NCHUNK * N * 4u)
#define OFF_S     (OFF_L + NCHUNK * N * 4u)
#define OFF_F1    (OFF_S + NCHUNK * N * 4u)   // feat1 bf16
#define OFF_F2    (OFF_F1 + N * D * 2u)       // feat2 bf16
#define OFF_PACK  (OFF_F2 + N * D * 2u)       // N*N/8 bytes = 8 MB packed simi

// Convert feats to bf16; compute sq2[j] = ||feat2_j||^2.
__global__ __launch_bounds__(256)
void prep_kernel(const float* __restrict__ f1, const float* __restrict__ f2,
                 unsigned short* __restrict__ f1b, unsigned short* __restrict__ f2b,
                 float* __restrict__ sq2) {
    const int w    = blockIdx.x * 4 + (threadIdx.x >> 6);  // 0..1023
    const int lane = threadIdx.x & 63;
    for (int row = w; row < N; row += 1024) {
        float a0 = f1[row * D + lane];
        float a1 = f1[row * D + 64 + lane];
        float b0 = f2[row * D + lane];
        float b1 = f2[row * D + 64 + lane];
        __hip_bfloat16 t;
        t = __float2bfloat16(a0); f1b[row * D + lane]      = *(unsigned short*)&t;
        t = __float2bfloat16(a1); f1b[row * D + 64 + lane] = *(unsigned short*)&t;
        t = __float2bfloat16(b0); f2b[row * D + lane]      = *(unsigned short*)&t;
        t = __float2bfloat16(b1); f2b[row * D + 64 + lane] = *(unsigned short*)&t;
        float ss = b0 * b0 + b1 * b1;
        #pragma unroll
        for (int off = 32; off > 0; off >>= 1) ss += __shfl_xor(ss, off);
        if (lane == 0) sq2[row] = ss;
    }
}

// Streaming pass: pack simi (int32 {+1,-1}) into 1 bit/entry (bit set iff ==1),
// natural column order; count positives. 256 MB -> 8 MB. Pure BW kernel:
// coalesced dword loads, ballot, lane-0 stores; no LDS, no barriers.
__global__ __launch_bounds__(256)
void pack_kernel(const int* __restrict__ simi, uint64* __restrict__ packed,
                 uint32* __restrict__ pos_acc) {
    const int row  = blockIdx.x;          // 0..N-1
    const int wave = threadIdx.x >> 6;    // 0..3
    const int lane = threadIdx.x & 63;
    const int* rp = simi + (size_t)row * N;
    uint32 pos = 0;
    // each wave-iteration covers 256 cols via 4 independent loads + 4 ballots
    for (int seg = wave; seg < N / 256; seg += 4) {
        const int cb = seg * 256;
        int v0 = rp[cb + lane];
        int v1 = rp[cb + 64 + lane];
        int v2 = rp[cb + 128 + lane];
        int v3 = rp[cb + 192 + lane];
        uint64 b0 = __ballot(v0 == 1);   // bit i <-> col cb + i
        uint64 b1 = __ballot(v1 == 1);
        uint64 b2 = __ballot(v2 == 1);
        uint64 b3 = __ballot(v3 == 1);
        if (lane == 0) {
            uint64* dst = packed + (size_t)row * (N / 64) + seg * 4;
            ulonglong2 p01 = {b0, b1}, p23 = {b2, b3};
            *reinterpret_cast<ulonglong2*>(dst)     = p01;
            *reinterpret_cast<ulonglong2*>(dst + 2) = p23;
            pos += (uint32)(__popcll(b0) + __popcll(b1) + __popcll(b2) + __popcll(b3));
        }
    }
    if (lane == 0 && pos) atomicAdd(pos_acc, pos);
}

// Fused GEMM + online softmax + masked accumulation.
// Block = (rowtile, chunk): rows [rowtile*128, +128), cols [chunk*512, +512).
// Wave owns 32 rows (2 sets of 16) so each B fragment read feeds 2 MFMAs.
// Column permutation: LDS B-position q holds global col c(q)=4*(q&15)+(q>>4),
// so acc[cf] lane lo holds global col cbase+4*lo+cf -> its 4 mask bits are
// contiguous in one packed u32 at shift 4*(lo&7). Softmax is perm-invariant.
__global__ __launch_bounds__(256)
void main_kernel(const unsigned short* __restrict__ f1b,
                 const unsigned short* __restrict__ f2b,
                 const float* __restrict__ sq2,
                 const uint32* __restrict__ packed32,
                 float* __restrict__ pm, float* __restrict__ pl, float* __restrict__ ps) {
    __shared__ unsigned short ldsB[CT * D];  // 16 KB, XOR-swizzled
    __shared__ float ldsSq[CHUNK];           // 2 KB

    const int tid  = threadIdx.x;
    const int wave = tid >> 6;
    const int lane = tid & 63;
    const int lo   = lane & 15;
    const int hi   = lane >> 4;

    const int rowtile = blockIdx.x;       // 0..63
    const int chunk   = blockIdx.y;       // 0..15
    const int rbase   = rowtile * RT + wave * 32;
    const int cbase0  = chunk * CHUNK;

    for (int i = tid; i < CHUNK; i += 256) ldsSq[i] = sq2[cbase0 + i];

    // A fragments: 2 sets of 16 rows, full K=128, resident for the sweep.
    bf16x8 afrag[2][4];
    #pragma unroll
    for (int a = 0; a < 2; a++) {
        const unsigned short* ap = f1b + (size_t)(rbase + a * 16 + lo) * D + hi * 8;
        #pragma unroll
        for (int kk = 0; kk < 4; kk++)
            afrag[a][kk] = *reinterpret_cast<const bf16x8*>(ap + kk * 32);
    }

    const int sq_ = (tid >> 4);           // staging: position within 16-group
    const int sg_ = tid & 15;             // staging: 16B chunk index

    // packed mask pointer: row rbase+hi*4(+a*16+r), word (cbase>>5)+(lo>>3)
    const uint32* pk = packed32 + (size_t)(rbase + hi * 4) * (N / 32)
                                + (cbase0 >> 5) + (lo >> 3);
    const int mshift = 4 * (lo & 7);

    float m[2][4], l[2][4], s[2][4];
    #pragma unroll
    for (int a = 0; a < 2; a++)
        #pragma unroll
        for (int r = 0; r < 4; r++) { m[a][r] = -1e30f; l[a][r] = 0.f; s[a][r] = 0.f; }

    for (int t = 0; t < NTILES; t++) {
        const int cbase = cbase0 + t * CT;

        // mask bits: one u32 per row (4 bits used), L3-resident (8 MB total)
        uint32 mb[2][4];
        #pragma unroll
        for (int a = 0; a < 2; a++)
            #pragma unroll
            for (int r = 0; r < 4; r++)
                mb[a][r] = (pk[(size_t)(a * 16 + r) * (N / 32)] >> mshift) & 0xfu;

        __syncthreads();  // previous tile's LDS reads complete
        // stage B tile: position q holds global col c(q)=4*(q&15)+(q>>4)
        #pragma unroll
        for (int it = 0; it < 4; it++) {
            int q = it * 16 + sq_;
            int c = 4 * (q & 15) + (q >> 4);
            const uint4 v = *reinterpret_cast<const uint4*>(f2b + (size_t)(cbase + c) * D + sg_ * 8);
            *reinterpret_cast<uint4*>(ldsB + q * D + ((sg_ ^ (q & 15)) * 8)) = v;
        }
        __syncthreads();

        // MFMA: 32 rows x 64 cols; each B fragment feeds both A sets
        f32x4 acc[2][4];
        #pragma unroll
        for (int cf = 0; cf < 4; cf++) {
            acc[0][cf] = (f32x4){0.f, 0.f, 0.f, 0.f};
            acc[1][cf] = (f32x4){0.f, 0.f, 0.f, 0.f};
            const int brow = cf * 16 + lo;
            #pragma unroll
            for (int kk = 0; kk < 4; kk++) {
                int g = kk * 4 + hi;
                bf16x8 b = *reinterpret_cast<const bf16x8*>(
                    ldsB + brow * D + ((g ^ (brow & 15)) * 8));
                acc[0][cf] = __builtin_amdgcn_mfma_f32_16x16x32_bf16(afrag[0][kk], b, acc[0][cf], 0, 0, 0);
                acc[1][cf] = __builtin_amdgcn_mfma_f32_16x16x32_bf16(afrag[1][kk], b, acc[1][cf], 0, 0, 0);
            }
        }

        // logits in-place: lg = 2c - sq2[col] (row-constant sq1 dropped)
        f32x4 sqv = *reinterpret_cast<const f32x4*>(&ldsSq[t * CT + 4 * lo]);
        #pragma unroll
        for (int a = 0; a < 2; a++) {
            #pragma unroll
            for (int cf = 0; cf < 4; cf++)
                #pragma unroll
                for (int r = 0; r < 4; r++)
                    acc[a][cf][r] = 2.0f * acc[a][cf][r] - sqv[cf];

            #pragma unroll
            for (int r = 0; r < 4; r++) {
                float tm = fmaxf(fmaxf(acc[a][0][r], acc[a][1][r]),
                                 fmaxf(acc[a][2][r], acc[a][3][r]));
                #pragma unroll
                for (int off = 1; off < 16; off <<= 1)
                    tm = fmaxf(tm, __shfl_xor(tm, off));
                float mn = fmaxf(m[a][r], tm);
                float al = __expf(m[a][r] - mn);
                l[a][r] *= al; s[a][r] *= al; m[a][r] = mn;
            }
            #pragma unroll
            for (int r = 0; r < 4; r++)
                #pragma unroll
                for (int cf = 0; cf < 4; cf++) {
                    float p = __expf(acc[a][cf][r] - m[a][r]);
                    l[a][r] += p;
                    if ((mb[a][r] >> cf) & 1u) s[a][r] += p;
                }
        }
        pk += 2;  // 64 cols = 2 u32 words
    }

    // reduce l,s across the 16-lane lo group (m already uniform over lo)
    #pragma unroll
    for (int a = 0; a < 2; a++) {
        #pragma unroll
        for (int r = 0; r < 4; r++) {
            #pragma unroll
            for (int off = 1; off < 16; off <<= 1) {
                l[a][r] += __shfl_xor(l[a][r], off);
                s[a][r] += __shfl_xor(s[a][r], off);
            }
        }
    }
    if (lo == 0) {
        #pragma unroll
        for (int a = 0; a < 2; a++)
            #pragma unroll
            for (int r = 0; r < 4; r++) {
                int row = rbase + a * 16 + hi * 4 + r;
                int idx = chunk * N + row;
                pm[idx] = m[a][r]; pl[idx] = l[a][r]; ps[idx] = s[a][r];
            }
    }
}

// Merge per-chunk (m,l,s) partials per row; accumulate sum of s/l.
__global__ void merge_kernel(const float* __restrict__ pm, const float* __restrict__ pl,
                             const float* __restrict__ ps, float* __restrict__ s_acc) {
    const int row = blockIdx.x * 256 + threadIdx.x;
    float M = -1e30f;
    #pragma unroll
    for (int k = 0; k < NCHUNK; k++) M = fmaxf(M, pm[k * N + row]);
    float L = 0.f, S = 0.f;
    #pragma unroll
    for (int k = 0; k < NCHUNK; k++) {
        float e = __expf(pm[k * N + row] - M);
        L += pl[k * N + row] * e;
        S += ps[k * N + row] * e;
    }
    float r = S / L;
    #pragma unroll
    for (int off = 32; off > 0; off >>= 1) r += __shfl_xor(r, off);
    __shared__ float red[4];
    int lane = threadIdx.x & 63, w = threadIdx.x >> 6;
    if (lane == 0) red[w] = r;
    __syncthreads();
    if (threadIdx.x == 0) atomicAdd(s_acc, red[0] + red[1] + red[2] + red[3]);
}

__global__ void final_kernel(const float* __restrict__ s_acc, const uint32* __restrict__ pos_acc,
                             float* __restrict__ out) {
    double S = (double)s_acc[0];
    double C = (double)N * (double)N - (double)pos_acc[0];  // count(simi != 1)
    double n = (double)N;
    out[0] = (float)((2.0 * S + C - n) / (n * n));
}

extern "C" void kernel_launch(void* const* d_in, const int* in_sizes, int n_in,
                              void* d_out, int out_size, void* d_ws, size_t ws_size,
                              hipStream_t stream) {
    const float* f1   = (const float*)d_in[0];
    const float* f2   = (const float*)d_in[1];
    const int*   simi = (const int*)d_in[2];
    float* out = (float*)d_out;
    char* ws = (char*)d_ws;

    float*  acc_s  = (float*)(ws + OFF_ACC);
    uint32* acc_p  = (uint32*)(ws + OFF_ACC + 4);
    float*  sq2    = (float*)(ws + OFF_SQ2);
    float*  pm     = (float*)(ws + OFF_M);
    float*  pl     = (float*)(ws + OFF_L);
    float*  ps     = (float*)(ws + OFF_S);
    unsigned short* f1b = (unsigned short*)(ws + OFF_F1);
    unsigned short* f2b = (unsigned short*)(ws + OFF_F2);
    uint64* packed = (uint64*)(ws + OFF_PACK);

    hipMemsetAsync(ws + OFF_ACC, 0, 64, stream);
    prep_kernel<<<256, 256, 0, stream>>>(f1, f2, f1b, f2b, sq2);
    pack_kernel<<<N, 256, 0, stream>>>(simi, packed, acc_p);
    main_kernel<<<dim3(N / RT, NCHUNK), 256, 0, stream>>>(f1b, f2b, sq2,
                                                          (const uint32*)packed, pm, pl, ps);
    merge_kernel<<<N / 256, 256, 0, stream>>>(pm, pl, ps, acc_s);
    final_kernel<<<1, 1, 0, stream>>>(acc_s, acc_p, out);
}

// Round 5
// 434.523 us; speedup vs baseline: 1.6845x; 1.6845x over previous
//
#include <hip/hip_runtime.h>
#include <hip/hip_bf16.h>
#include <stdint.h>

#define N 8192
#define D 128
#define NCHUNK 16
#define CHUNK (N / NCHUNK)      // 512 cols per chunk
#define RT 128                  // rows per block (4 waves x 32)
#define CT 64                   // cols per LDS tile
#define NTILES (CHUNK / CT)     // 8

typedef short bf16x8 __attribute__((ext_vector_type(8)));
typedef float f32x4 __attribute__((ext_vector_type(4)));
typedef unsigned int uint32;
typedef unsigned long long uint64;

// ---- workspace layout (bytes) ----
#define OFF_ACC   0u                          // [0] float S_sum, [4] uint32 P_count
#define OFF_SQ2   1024u                       // 8192 floats
#define OFF_RPOS  (OFF_SQ2 + N * 4u)          // N uint32 per-row positive counts
#define OFF_M     (OFF_RPOS + N * 4u)         // NCHUNK*N floats
#define OFF_L     (OFF_M + NCHUNK * N * 4u)
#define OFF_S     (OFF_L + NCHUNK * N * 4u)
#define OFF_F1    (OFF_S + NCHUNK * N * 4u)   // feat1 bf16
#define OFF_F2    (OFF_F1 + N * D * 2u)       // feat2 bf16
#define OFF_PACK  (OFF_F2 + N * D * 2u)       // N*N/8 bytes = 8 MB packed simi

// Convert feats to bf16; compute sq2[j] = ||feat2_j||^2.
__global__ __launch_bounds__(256)
void prep_kernel(const float* __restrict__ f1, const float* __restrict__ f2,
                 unsigned short* __restrict__ f1b, unsigned short* __restrict__ f2b,
                 float* __restrict__ sq2) {
    const int w    = blockIdx.x * 4 + (threadIdx.x >> 6);  // 0..1023
    const int lane = threadIdx.x & 63;
    for (int row = w; row < N; row += 1024) {
        float a0 = f1[row * D + lane];
        float a1 = f1[row * D + 64 + lane];
        float b0 = f2[row * D + lane];
        float b1 = f2[row * D + 64 + lane];
        __hip_bfloat16 t;
        t = __float2bfloat16(a0); f1b[row * D + lane]      = *(unsigned short*)&t;
        t = __float2bfloat16(a1); f1b[row * D + 64 + lane] = *(unsigned short*)&t;
        t = __float2bfloat16(b0); f2b[row * D + lane]      = *(unsigned short*)&t;
        t = __float2bfloat16(b1); f2b[row * D + 64 + lane] = *(unsigned short*)&t;
        float ss = b0 * b0 + b1 * b1;
        #pragma unroll
        for (int off = 32; off > 0; off >>= 1) ss += __shfl_xor(ss, off);
        if (lane == 0) sq2[row] = ss;
    }
}

// Streaming pass: pack simi (int32 {+1,-1}) into 1 bit/entry (bit set iff ==1),
// natural column order; per-row positive count to rowpos[row] (plain store).
// NO global atomics — round 4's 32k same-address atomicAdds serialized the
// whole kernel (394 us @ 2% VALU). One row per wave, 2048 co-resident blocks.
__global__ __launch_bounds__(256)
void pack_kernel(const int* __restrict__ simi, uint64* __restrict__ packed,
                 uint32* __restrict__ rowpos) {
    const int wave = threadIdx.x >> 6;
    const int lane = threadIdx.x & 63;
    const int row  = blockIdx.x * 4 + wave;   // 0..N-1
    const int* rp = simi + (size_t)row * N;
    uint64* dstrow = packed + (size_t)row * (N / 64);
    uint32 pos = 0;
    #pragma unroll 2
    for (int seg = 0; seg < N / 256; seg++) {
        const int cb = seg * 256;
        int v0 = rp[cb + lane];
        int v1 = rp[cb + 64 + lane];
        int v2 = rp[cb + 128 + lane];
        int v3 = rp[cb + 192 + lane];
        uint64 b0 = __ballot(v0 == 1);   // bit i <-> col cb + i
        uint64 b1 = __ballot(v1 == 1);
        uint64 b2 = __ballot(v2 == 1);
        uint64 b3 = __ballot(v3 == 1);
        if (lane == 0) {
            ulonglong2 p01 = {b0, b1}, p23 = {b2, b3};
            *reinterpret_cast<ulonglong2*>(dstrow + seg * 4)     = p01;
            *reinterpret_cast<ulonglong2*>(dstrow + seg * 4 + 2) = p23;
            pos += (uint32)(__popcll(b0) + __popcll(b1) + __popcll(b2) + __popcll(b3));
        }
    }
    if (lane == 0) rowpos[row] = pos;
}

// Fused GEMM + online softmax + masked accumulation.
// Block = (rowtile, chunk): rows [rowtile*128, +128), cols [chunk*512, +512).
// Wave owns 32 rows (2 sets of 16) so each B fragment read feeds 2 MFMAs.
// Column permutation: LDS B-position q holds global col c(q)=4*(q&15)+(q>>4),
// so acc[cf] lane lo holds global col cbase+4*lo+cf -> its 4 mask bits are
// contiguous in one packed u32 at shift 4*(lo&7). Softmax is perm-invariant.
__global__ __launch_bounds__(256)
void main_kernel(const unsigned short* __restrict__ f1b,
                 const unsigned short* __restrict__ f2b,
                 const float* __restrict__ sq2,
                 const uint32* __restrict__ packed32,
                 float* __restrict__ pm, float* __restrict__ pl, float* __restrict__ ps) {
    __shared__ unsigned short ldsB[CT * D];  // 16 KB, XOR-swizzled
    __shared__ float ldsSq[CHUNK];           // 2 KB

    const int tid  = threadIdx.x;
    const int wave = tid >> 6;
    const int lane = tid & 63;
    const int lo   = lane & 15;
    const int hi   = lane >> 4;

    const int rowtile = blockIdx.x;       // 0..63
    const int chunk   = blockIdx.y;       // 0..15
    const int rbase   = rowtile * RT + wave * 32;
    const int cbase0  = chunk * CHUNK;

    for (int i = tid; i < CHUNK; i += 256) ldsSq[i] = sq2[cbase0 + i];

    // A fragments: 2 sets of 16 rows, full K=128, resident for the sweep.
    bf16x8 afrag[2][4];
    #pragma unroll
    for (int a = 0; a < 2; a++) {
        const unsigned short* ap = f1b + (size_t)(rbase + a * 16 + lo) * D + hi * 8;
        #pragma unroll
        for (int kk = 0; kk < 4; kk++)
            afrag[a][kk] = *reinterpret_cast<const bf16x8*>(ap + kk * 32);
    }

    const int sq_ = (tid >> 4);           // staging: position within 16-group
    const int sg_ = tid & 15;             // staging: 16B chunk index

    // packed mask pointer: row rbase+hi*4(+a*16+r), word (cbase>>5)+(lo>>3)
    const uint32* pk = packed32 + (size_t)(rbase + hi * 4) * (N / 32)
                                + (cbase0 >> 5) + (lo >> 3);
    const int mshift = 4 * (lo & 7);

    float m[2][4], l[2][4], s[2][4];
    #pragma unroll
    for (int a = 0; a < 2; a++)
        #pragma unroll
        for (int r = 0; r < 4; r++) { m[a][r] = -1e30f; l[a][r] = 0.f; s[a][r] = 0.f; }

    for (int t = 0; t < NTILES; t++) {
        const int cbase = cbase0 + t * CT;

        // mask bits: one u32 per row (4 bits used), L3-resident (8 MB total)
        uint32 mb[2][4];
        #pragma unroll
        for (int a = 0; a < 2; a++)
            #pragma unroll
            for (int r = 0; r < 4; r++)
                mb[a][r] = (pk[(size_t)(a * 16 + r) * (N / 32)] >> mshift) & 0xfu;

        __syncthreads();  // previous tile's LDS reads complete
        // stage B tile: position q holds global col c(q)=4*(q&15)+(q>>4)
        #pragma unroll
        for (int it = 0; it < 4; it++) {
            int q = it * 16 + sq_;
            int c = 4 * (q & 15) + (q >> 4);
            const uint4 v = *reinterpret_cast<const uint4*>(f2b + (size_t)(cbase + c) * D + sg_ * 8);
            *reinterpret_cast<uint4*>(ldsB + q * D + ((sg_ ^ (q & 15)) * 8)) = v;
        }
        __syncthreads();

        // MFMA: 32 rows x 64 cols; each B fragment feeds both A sets
        f32x4 acc[2][4];
        #pragma unroll
        for (int cf = 0; cf < 4; cf++) {
            acc[0][cf] = (f32x4){0.f, 0.f, 0.f, 0.f};
            acc[1][cf] = (f32x4){0.f, 0.f, 0.f, 0.f};
            const int brow = cf * 16 + lo;
            #pragma unroll
            for (int kk = 0; kk < 4; kk++) {
                int g = kk * 4 + hi;
                bf16x8 b = *reinterpret_cast<const bf16x8*>(
                    ldsB + brow * D + ((g ^ (brow & 15)) * 8));
                acc[0][cf] = __builtin_amdgcn_mfma_f32_16x16x32_bf16(afrag[0][kk], b, acc[0][cf], 0, 0, 0);
                acc[1][cf] = __builtin_amdgcn_mfma_f32_16x16x32_bf16(afrag[1][kk], b, acc[1][cf], 0, 0, 0);
            }
        }

        // logits in-place: lg = 2c - sq2[col] (row-constant sq1 dropped)
        f32x4 sqv = *reinterpret_cast<const f32x4*>(&ldsSq[t * CT + 4 * lo]);
        #pragma unroll
        for (int a = 0; a < 2; a++) {
            #pragma unroll
            for (int cf = 0; cf < 4; cf++)
                #pragma unroll
                for (int r = 0; r < 4; r++)
                    acc[a][cf][r] = 2.0f * acc[a][cf][r] - sqv[cf];

            #pragma unroll
            for (int r = 0; r < 4; r++) {
                float tm = fmaxf(fmaxf(acc[a][0][r], acc[a][1][r]),
                                 fmaxf(acc[a][2][r], acc[a][3][r]));
                #pragma unroll
                for (int off = 1; off < 16; off <<= 1)
                    tm = fmaxf(tm, __shfl_xor(tm, off));
                float mn = fmaxf(m[a][r], tm);
                float al = __expf(m[a][r] - mn);
                l[a][r] *= al; s[a][r] *= al; m[a][r] = mn;
            }
            #pragma unroll
            for (int r = 0; r < 4; r++)
                #pragma unroll
                for (int cf = 0; cf < 4; cf++) {
                    float p = __expf(acc[a][cf][r] - m[a][r]);
                    l[a][r] += p;
                    if ((mb[a][r] >> cf) & 1u) s[a][r] += p;
                }
        }
        pk += 2;  // 64 cols = 2 u32 words
    }

    // reduce l,s across the 16-lane lo group (m already uniform over lo)
    #pragma unroll
    for (int a = 0; a < 2; a++) {
        #pragma unroll
        for (int r = 0; r < 4; r++) {
            #pragma unroll
            for (int off = 1; off < 16; off <<= 1) {
                l[a][r] += __shfl_xor(l[a][r], off);
                s[a][r] += __shfl_xor(s[a][r], off);
            }
        }
    }
    if (lo == 0) {
        #pragma unroll
        for (int a = 0; a < 2; a++)
            #pragma unroll
            for (int r = 0; r < 4; r++) {
                int row = rbase + a * 16 + hi * 4 + r;
                int idx = chunk * N + row;
                pm[idx] = m[a][r]; pl[idx] = l[a][r]; ps[idx] = s[a][r];
            }
    }
}

// Merge per-chunk (m,l,s) partials per row; accumulate sum of s/l and the
// positive count. One atomic per block per accumulator (32 blocks total).
__global__ void merge_kernel(const float* __restrict__ pm, const float* __restrict__ pl,
                             const float* __restrict__ ps, const uint32* __restrict__ rowpos,
                             float* __restrict__ s_acc, uint32* __restrict__ pos_acc) {
    const int row = blockIdx.x * 256 + threadIdx.x;
    float M = -1e30f;
    #pragma unroll
    for (int k = 0; k < NCHUNK; k++) M = fmaxf(M, pm[k * N + row]);
    float L = 0.f, S = 0.f;
    #pragma unroll
    for (int k = 0; k < NCHUNK; k++) {
        float e = __expf(pm[k * N + row] - M);
        L += pl[k * N + row] * e;
        S += ps[k * N + row] * e;
    }
    float r = S / L;
    uint32 pc = rowpos[row];
    #pragma unroll
    for (int off = 32; off > 0; off >>= 1) {
        r  += __shfl_xor(r, off);
        pc += __shfl_xor(pc, off);
    }
    __shared__ float red[4];
    __shared__ uint32 redp[4];
    int lane = threadIdx.x & 63, w = threadIdx.x >> 6;
    if (lane == 0) { red[w] = r; redp[w] = pc; }
    __syncthreads();
    if (threadIdx.x == 0) {
        atomicAdd(s_acc, red[0] + red[1] + red[2] + red[3]);
        atomicAdd(pos_acc, redp[0] + redp[1] + redp[2] + redp[3]);
    }
}

__global__ void final_kernel(const float* __restrict__ s_acc, const uint32* __restrict__ pos_acc,
                             float* __restrict__ out) {
    double S = (double)s_acc[0];
    double C = (double)N * (double)N - (double)pos_acc[0];  // count(simi != 1)
    double n = (double)N;
    out[0] = (float)((2.0 * S + C - n) / (n * n));
}

extern "C" void kernel_launch(void* const* d_in, const int* in_sizes, int n_in,
                              void* d_out, int out_size, void* d_ws, size_t ws_size,
                              hipStream_t stream) {
    const float* f1   = (const float*)d_in[0];
    const float* f2   = (const float*)d_in[1];
    const int*   simi = (const int*)d_in[2];
    float* out = (float*)d_out;
    char* ws = (char*)d_ws;

    float*  acc_s  = (float*)(ws + OFF_ACC);
    uint32* acc_p  = (uint32*)(ws + OFF_ACC + 4);
    float*  sq2    = (float*)(ws + OFF_SQ2);
    uint32* rowpos = (uint32*)(ws + OFF_RPOS);
    float*  pm     = (float*)(ws + OFF_M);
    float*  pl     = (float*)(ws + OFF_L);
    float*  ps     = (float*)(ws + OFF_S);
    unsigned short* f1b = (unsigned short*)(ws + OFF_F1);
    unsigned short* f2b = (unsigned short*)(ws + OFF_F2);
    uint64* packed = (uint64*)(ws + OFF_PACK);

    hipMemsetAsync(ws + OFF_ACC, 0, 64, stream);
    prep_kernel<<<256, 256, 0, stream>>>(f1, f2, f1b, f2b, sq2);
    pack_kernel<<<N / 4, 256, 0, stream>>>(simi, packed, rowpos);
    main_kernel<<<dim3(N / RT, NCHUNK), 256, 0, stream>>>(f1b, f2b, sq2,
                                                          (const uint32*)packed, pm, pl, ps);
    merge_kernel<<<N / 256, 256, 0, stream>>>(pm, pl, ps, rowpos, acc_s, acc_p);
    final_kernel<<<1, 1, 0, stream>>>(acc_s, acc_p, out);
}